// Round 6
// baseline (494.148 us; speedup 1.0000x reference)
//
#include <hip/hip_runtime.h>
#include <math.h>
#include <stdint.h>

#define NPTS   1048576
#define NLEV   16
#define TPB    256
#define PPT    8                   // points per thread in gather phase
#define CHUNK  (TPB * PPT)         // 2048 points per gather block
#define ROW    35                  // 3 (x) + 16 levels * 2 feats
#define TBL_ENTRIES (1u << 19)

typedef float f4 __attribute__((ext_vector_type(4)));
typedef float f2 __attribute__((ext_vector_type(2)));

struct LevelParams {
    float    resf;
    uint32_t hm;
    uint32_t is_pow2;
    uint32_t use_nt;     // table > 1MB: bypass L1 (nt) on gathers
    uint64_t magic;      // Lemire fastmod: ~0ull/hm + 1 (unused when pow2)
};
struct LPAll { LevelParams lv[NLEV]; };

__device__ __forceinline__ void hash_gather_point(
    float xv0, float xv1, float xv2,
    const LevelParams& P, const f2* __restrict__ tbl,
    float& acc0, float& acc1)
{
    const float xs0 = xv0 * P.resf, xs1 = xv1 * P.resf, xs2 = xv2 * P.resf;
    const float f0 = floorf(xs0), f1 = floorf(xs1), f2v = floorf(xs2);
    const float t0 = xs0 - f0, t1 = xs1 - f1, t2 = xs2 - f2v;

    const unsigned a0 = (unsigned)(int)f0;
    const unsigned a1 = a0 + 1u;
    const unsigned b0 = (unsigned)(int)f1 * 2654435761u;
    const unsigned b1 = ((unsigned)(int)f1 + 1u) * 2654435761u;
    const unsigned c0 = (unsigned)(int)f2v * 805459861u;
    const unsigned c1 = ((unsigned)(int)f2v + 1u) * 805459861u;

    const float wa0 = 1.f - t0, wa1 = t0;
    const float wb0 = 1.f - t1, wb1 = t1;
    const float wc0 = 1.f - t2, wc1 = t2;

    const uint32_t hmv  = P.hm;
    const uint32_t mask = hmv - 1u;
    const uint64_t M    = P.magic;
    const bool     p2   = (P.is_pow2 != 0);   // uniform per block
    const bool     nt   = (P.use_nt != 0);    // uniform per block

    // compute all 8 indices first, then issue all 8 loads back-to-back so
    // the 8 gathers stay in flight together (vmcnt pipelining)
    unsigned hi[8];
    #pragma unroll
    for (int n = 0; n < 8; ++n) {
        unsigned h = ((n & 1) ? a1 : a0)
                   ^ ((n & 2) ? b1 : b0)
                   ^ ((n & 4) ? c1 : c0);
        if (p2) {
            hi[n] = h & mask;
        } else {
            uint64_t low = M * (uint64_t)h;       // Lemire fastmod_u32, exact
            hi[n] = (uint32_t)(((__uint128_t)low * hmv) >> 64);
        }
    }
    f2 e[8];
    #pragma unroll
    for (int n = 0; n < 8; ++n)
        e[n] = nt ? __builtin_nontemporal_load(&tbl[hi[n]]) : tbl[hi[n]];

    acc0 = 0.f; acc1 = 0.f;
    #pragma unroll
    for (int n = 0; n < 8; ++n) {
        float w = (((n & 1) ? wa1 : wa0) * ((n & 2) ? wb1 : wb0))
                  * ((n & 4) ? wc1 : wc0);
        acc0 = fmaf(e[n].x, w, acc0);
        acc1 = fmaf(e[n].y, w, acc1);
    }
}

// Phase 1: one block = (level, 2048-point chunk); blockIdx%8 -> level ->
// XCD-pinned so each level's <=4MB table is L2-resident. No LDS, no barriers:
// occupancy capped only by VGPRs. Feature pairs go level-major into ws.
__global__ __launch_bounds__(TPB)
void hashgrid_gather(const float* __restrict__ x,
                     const float* __restrict__ tables,
                     float* __restrict__ ws,
                     LPAll lp, int base)
{
    const int tid = threadIdx.x;
    const int lvl = base + (blockIdx.x & 7);
    const int p0  = (blockIdx.x >> 3) * CHUNK;

    const LevelParams P   = lp.lv[lvl];
    const f2*         tbl = (const f2*)(tables + (size_t)lvl * TBL_ENTRIES * 2);
    const float*      xp  = x + (size_t)p0 * 3;
    f2* wrow = (f2*)ws + (size_t)lvl * NPTS + p0;

    #pragma unroll
    for (int k = 0; k < PPT; ++k) {
        const int pi = tid + k * TPB;
        // stride-12B per lane: wave covers 768B contiguous -> coalesced
        const float xv0 = __builtin_nontemporal_load(&xp[pi * 3 + 0]);
        const float xv1 = __builtin_nontemporal_load(&xp[pi * 3 + 1]);
        const float xv2 = __builtin_nontemporal_load(&xp[pi * 3 + 2]);
        float acc0, acc1;
        hash_gather_point(xv0, xv1, xv2, P, tbl, acc0, acc1);
        f2 v; v.x = acc0; v.y = acc1;
        __builtin_nontemporal_store(v, &wrow[pi]);   // nt: don't evict table
    }
}

// Phase 2: streaming interleave ws (level-major) + x -> row-major out,
// flushed as full float4 lines.
__global__ __launch_bounds__(TPB)
void hashgrid_interleave(const float* __restrict__ x,
                         const float* __restrict__ ws,
                         float* __restrict__ out)
{
    __shared__ float srow[TPB * ROW];
    const int tid = threadIdx.x;
    const int p0  = blockIdx.x * TPB;

    const float* xblk = x + (size_t)p0 * 3;
    #pragma unroll
    for (int j = 0; j < 3; ++j) {
        int idx = tid + j * TPB;
        int p = idx / 3, c = idx - p * 3;
        srow[p * ROW + c] = __builtin_nontemporal_load(&xblk[idx]);
    }
    const f2* wsv = (const f2*)ws;
    #pragma unroll
    for (int l = 0; l < NLEV; ++l) {
        f2 v = __builtin_nontemporal_load(&wsv[(size_t)l * NPTS + p0 + tid]);
        srow[tid * ROW + 3 + 2 * l] = v.x;
        srow[tid * ROW + 4 + 2 * l] = v.y;
    }
    __syncthreads();

    f4*       outv = (f4*)(out + (size_t)p0 * ROW);
    const f4* sv   = (const f4*)srow;
    for (int j = tid; j < (TPB * ROW) / 4; j += TPB)
        __builtin_nontemporal_store(sv[j], &outv[j]);
}

// Fallback (ws too small): direct scattered-store path.
__global__ __launch_bounds__(TPB)
void hashgrid_lvl(const float* __restrict__ x,
                  const float* __restrict__ tables,
                  float* __restrict__ out,
                  LPAll lp, int base)
{
    const int tid = threadIdx.x;
    const int lvl = base + (blockIdx.x & 7);
    const int p0  = (blockIdx.x >> 3) * TPB;

    const float* xp = x + (size_t)p0 * 3;
    const float xv0 = xp[tid * 3 + 0];
    const float xv1 = xp[tid * 3 + 1];
    const float xv2 = xp[tid * 3 + 2];

    const LevelParams P   = lp.lv[lvl];
    const f2*         tbl = (const f2*)(tables + (size_t)lvl * TBL_ENTRIES * 2);
    float acc0, acc1;
    hash_gather_point(xv0, xv1, xv2, P, tbl, acc0, acc1);

    float* orow = out + (size_t)(p0 + tid) * ROW;
    __builtin_nontemporal_store(acc0, &orow[3 + 2 * lvl]);
    __builtin_nontemporal_store(acc1, &orow[4 + 2 * lvl]);
    if (lvl == 0) {
        __builtin_nontemporal_store(xv0, &orow[0]);
        __builtin_nontemporal_store(xv1, &orow[1]);
        __builtin_nontemporal_store(xv2, &orow[2]);
    }
}

extern "C" void kernel_launch(void* const* d_in, const int* in_sizes, int n_in,
                              void* d_out, int out_size, void* d_ws, size_t ws_size,
                              hipStream_t stream)
{
    const float* x      = (const float*)d_in[0];
    const float* tables = (const float*)d_in[1];
    float*       out    = (float*)d_out;

    // Host-side level params with system libm -> bit-identical to CPython math.
    LPAll lp;
    const double beta = exp((log(2048.0) - log(16.0)) / 15.0);
    for (int i = 0; i < NLEV; ++i) {
        double r = floor(16.0 * pow(beta, (double)i));
        double h3 = r * r * r;                 // res^3, exact in double
        uint32_t hm = (h3 < (double)(1u << 19)) ? (uint32_t)h3 : (1u << 19);
        lp.lv[i].resf    = (float)r;
        lp.lv[i].hm      = hm;
        lp.lv[i].is_pow2 = ((hm & (hm - 1u)) == 0u) ? 1u : 0u;
        lp.lv[i].use_nt  = ((size_t)hm * 8 > (1u << 20)) ? 1u : 0u;
        lp.lv[i].magic   = lp.lv[i].is_pow2 ? 0ull : (~0ull / hm + 1ull);
    }

    const size_t ws_need = (size_t)NLEV * NPTS * 2 * sizeof(float);  // 128 MB
    if (ws_size >= ws_need) {
        const int gblocks = 8 * (NPTS / CHUNK);   // 8 levels x 512 chunks
        hashgrid_gather<<<gblocks, TPB, 0, stream>>>(x, tables, (float*)d_ws, lp, 0);
        hashgrid_gather<<<gblocks, TPB, 0, stream>>>(x, tables, (float*)d_ws, lp, 8);
        hashgrid_interleave<<<NPTS / TPB, TPB, 0, stream>>>(x, (const float*)d_ws, out);
    } else {
        const int nblocks = 8 * (NPTS / TPB);
        hashgrid_lvl<<<nblocks, TPB, 0, stream>>>(x, tables, out, lp, 0);
        hashgrid_lvl<<<nblocks, TPB, 0, stream>>>(x, tables, out, lp, 8);
    }
}